// Round 15
// baseline (313.876 us; speedup 1.0000x reference)
//
#include <hip/hip_runtime.h>
#include <hip/hip_bf16.h>
#include <cstddef>
#include <cstdint>

// Problem constants (fixed by the reference setup)
#define N_B   8
#define L_L   4096
#define S_S   4096
#define H_H   8
#define D_D   64
#define NH    64          // N_B * H_H
// KV_aug layout (d-major): rows 0..63 = KV[d][v] (stride 68, cols 64..67 pad),
// row 64 = K_sum[d] (indexed by d in cols 0..63). KVSZ floats per (n,h).
#define KVLD  68
#define KVSZ  (65 * KVLD)   // 4420
#define TSTRIDE (32 * H_H * D_D)   // floats per 32-row tile step

typedef const float __attribute__((address_space(1)))* gas_fp;
typedef float __attribute__((address_space(3)))* las_fp;

__device__ __forceinline__ float elu1(float x) {
    // elu(x)+1 : x>0 ? x+1 : exp(x)
    return x > 0.f ? x + 1.f : __expf(x);
}

// ---------------------------------------------------------------------------
// Phase 1 (v10): K+V double-buffered DMA (v9 schedule) with a register-lean
// implementation.
//  v9 ledger: right schedule, but WRITE 253MB = ~28 acc regs spilled/reloaded
//  per tile — the per-tile 64-bit address recomputation for 4 DMAs + runtime
//  buf indexing tipped RA past the 128-reg cap (acc=64 leaves no slack).
//  v10: (1) 4 per-lane source pointers computed ONCE, advanced by constant
//  TSTRIDE per issue (no per-tile address math); (2) tile loop unrolled by 2
//  so the double-buffer index is COMPILE-TIME (named K0/K1/V0/V1, no runtime
//  selects; ntiles=128/split always even). Per half-iter: issue 4 DMAs ->
//  vmcnt(4) (current arrived, next in flight) -> wave-private elu fixup ->
//  compute. Zero barriers; wave w owns s-rows w*8..w*8+7. ~100 regs < 128.
// ---------------------------------------------------------------------------
__global__ __launch_bounds__(256, 4)
void la_phase1(const float* __restrict__ Kin, const float* __restrict__ Vin,
               float* __restrict__ partials, int split, int schunk)
{
    __shared__ union {
        struct { float K0[32 * 64]; float K1[32 * 64];
                 float V0[32 * 64]; float V1[32 * 64]; } st;   // 32 KB
        float acc[64 * 68];                                    // 17.3 KB
    } sm;
    __shared__ float sKsumP[4 * 64];     // per-wave ksum partials

    const int b     = blockIdx.x;
    const int nh    = b / split;
    const int chunk = b - nh * split;
    const int n     = nh >> 3;
    const int h     = nh & 7;
    const int s0    = chunk * schunk;

    const int tid  = threadIdx.x;
    const int w    = tid >> 6;
    const int lane = tid & 63;
    const int dg   = lane >> 3;   // d-group: d = dg*8 + i
    const int vg   = lane & 7;    // v-group: v = vg*8 + j

    float acc[8][8];
    #pragma unroll
    for (int i = 0; i < 8; ++i)
        #pragma unroll
        for (int j = 0; j < 8; ++j) acc[i][j] = 0.f;
    float ksum = 0.f;

    const int kd = lane;               // ksum d index (per-wave full coverage)

    // DMA map: chunk c covers rows w*8+c*4..+3; lane l -> row +(l>>4),
    // col (l&15)*4 (16B); LDS dest linear at float idx (w*8+c*4)*64 + l*4.
    const int lrow = lane >> 4;        // 0..3
    const int lcol = (lane & 15) * 4;  // float col

    // 4 per-lane source pointers, advanced by TSTRIDE per issue (no per-tile
    // address math -> no register-pressure leak).
    const size_t base = (size_t)n * S_S * (H_H * D_D) + h * D_D;
    const float* kp0 = Kin + base + (size_t)(s0 + w * 8 + 0 + lrow) * (H_H * D_D) + lcol;
    const float* kp1 = Kin + base + (size_t)(s0 + w * 8 + 4 + lrow) * (H_H * D_D) + lcol;
    const float* vp0 = Vin + base + (size_t)(s0 + w * 8 + 0 + lrow) * (H_H * D_D) + lcol;
    const float* vp1 = Vin + base + (size_t)(s0 + w * 8 + 4 + lrow) * (H_H * D_D) + lcol;

    const int ntiles = schunk >> 5;    // tiles of 32 s-rows; 128/split, even
    const int nt2    = ntiles >> 1;

    const int kb0 = (w * 8 + 0) * 64;  // LDS chunk bases (compile-time-ish)
    const int kb1 = (w * 8 + 4) * 64;

#define ISSUE_TILE(KB, VB)                                                       \
    do {                                                                         \
        __builtin_amdgcn_global_load_lds((gas_fp)kp0, (las_fp)&KB[kb0], 16, 0, 0); \
        __builtin_amdgcn_global_load_lds((gas_fp)kp1, (las_fp)&KB[kb1], 16, 0, 0); \
        __builtin_amdgcn_global_load_lds((gas_fp)vp0, (las_fp)&VB[kb0], 16, 0, 0); \
        __builtin_amdgcn_global_load_lds((gas_fp)vp1, (las_fp)&VB[kb1], 16, 0, 0); \
        kp0 += TSTRIDE; kp1 += TSTRIDE; vp0 += TSTRIDE; vp1 += TSTRIDE;          \
    } while (0)

#define FIXUP_K(KB)                                                              \
    do {                                                                         \
        float* p0_ = &KB[kb0 + lane * 4];                                        \
        float4 a_ = *(const float4*)p0_;                                         \
        a_.x = elu1(a_.x); a_.y = elu1(a_.y); a_.z = elu1(a_.z); a_.w = elu1(a_.w); \
        *(float4*)p0_ = a_;                                                      \
        float* p1_ = &KB[kb1 + lane * 4];                                        \
        float4 b_ = *(const float4*)p1_;                                         \
        b_.x = elu1(b_.x); b_.y = elu1(b_.y); b_.z = elu1(b_.z); b_.w = elu1(b_.w); \
        *(float4*)p1_ = b_;                                                      \
    } while (0)

#define COMPUTE_TILE(KB, VB)                                                     \
    do {                                                                         \
        _Pragma("unroll")                                                        \
        for (int sl = 0; sl < 8; ++sl) {                                         \
            const int s_ = w * 8 + sl;                                           \
            const float4 k0_ = *(const float4*)&KB[s_ * 64 + dg * 8];            \
            const float4 k1_ = *(const float4*)&KB[s_ * 64 + dg * 8 + 4];        \
            const float4 v0_ = *(const float4*)&VB[s_ * 64 + vg * 8];            \
            const float4 v1_ = *(const float4*)&VB[s_ * 64 + vg * 8 + 4];        \
            const float kf_[8] = {k0_.x, k0_.y, k0_.z, k0_.w,                    \
                                  k1_.x, k1_.y, k1_.z, k1_.w};                   \
            const float vf_[8] = {v0_.x, v0_.y, v0_.z, v0_.w,                    \
                                  v1_.x, v1_.y, v1_.z, v1_.w};                   \
            _Pragma("unroll")                                                    \
            for (int i = 0; i < 8; ++i)                                          \
                _Pragma("unroll")                                                \
                for (int j = 0; j < 8; ++j)                                      \
                    acc[i][j] = fmaf(kf_[i], vf_[j], acc[i][j]);                 \
        }                                                                        \
        _Pragma("unroll")                                                        \
        for (int sl = 0; sl < 8; ++sl)                                           \
            ksum += KB[(w * 8 + sl) * 64 + kd];                                  \
    } while (0)

    // ---- prologue: tile 0 -> buffers 0 ----
    ISSUE_TILE(sm.st.K0, sm.st.V0);

    for (int tt = 0; tt < nt2; ++tt) {
        // half A: prefetch tile 2tt+1 -> buf1, consume buf0 (tile 2tt)
        ISSUE_TILE(sm.st.K1, sm.st.V1);
        asm volatile("s_waitcnt vmcnt(4)" ::: "memory");
        FIXUP_K(sm.st.K0);
        COMPUTE_TILE(sm.st.K0, sm.st.V0);

        // half B: prefetch tile 2tt+2 -> buf0 (if any), consume buf1
        if (tt + 1 < nt2) {
            ISSUE_TILE(sm.st.K0, sm.st.V0);
            asm volatile("s_waitcnt vmcnt(4)" ::: "memory");
        } else {
            asm volatile("s_waitcnt vmcnt(0)" ::: "memory");
        }
        FIXUP_K(sm.st.K1);
        COMPUTE_TILE(sm.st.K1, sm.st.V1);
    }
#undef ISSUE_TILE
#undef FIXUP_K
#undef COMPUTE_TILE

    __syncthreads();   // loop done (implicit full drain); sm.acc (union) safe

    // cross-wave reduce of acc into sm.acc[d][v] (stride 68), sequential & exact
    for (int ww = 0; ww < 4; ++ww) {
        if (w == ww) {
            #pragma unroll
            for (int i = 0; i < 8; ++i) {
                float* p = &sm.acc[(dg * 8 + i) * 68 + vg * 8];
                if (ww == 0) {
                    *(float4*)p       = make_float4(acc[i][0], acc[i][1], acc[i][2], acc[i][3]);
                    *(float4*)(p + 4) = make_float4(acc[i][4], acc[i][5], acc[i][6], acc[i][7]);
                } else {
                    float4 a0 = *(const float4*)p;
                    float4 a1 = *(const float4*)(p + 4);
                    a0.x += acc[i][0]; a0.y += acc[i][1]; a0.z += acc[i][2]; a0.w += acc[i][3];
                    a1.x += acc[i][4]; a1.y += acc[i][5]; a1.z += acc[i][6]; a1.w += acc[i][7];
                    *(float4*)p       = a0;
                    *(float4*)(p + 4) = a1;
                }
            }
        }
        __syncthreads();
    }

    // ksum: deterministic 4-way reduce (one slot per (wave, d))
    sKsumP[w * 64 + kd] = ksum;
    __syncthreads();

    // write this block's partial KV_aug[65][68] d-major (row 64 = K_sum, pads 0)
    float* outp = partials + (size_t)b * KVSZ;
    for (int idx = tid; idx < KVSZ; idx += 256) {
        const int r = idx / KVLD;
        const int c = idx - r * KVLD;
        float val = 0.f;
        if (c < 64) {
            if (r < 64)
                val = sm.acc[idx];   // sm.acc is [d][v] stride 68 == same layout
            else
                val = sKsumP[c] + sKsumP[64 + c] + sKsumP[128 + c] + sKsumP[192 + c];
        }
        outp[idx] = val;
    }
}

// ---------------------------------------------------------------------------
// Reduce: sum the `split` partials per (n,h) -> kvt[nh][65][68]
// ---------------------------------------------------------------------------
__global__ __launch_bounds__(256)
void la_reduce(const float* __restrict__ partials, float* __restrict__ kvt, int split)
{
    const int idx = blockIdx.x * 256 + threadIdx.x;
    if (idx >= NH * KVSZ) return;
    const int nh  = idx / KVSZ;
    const int rem = idx - nh * KVSZ;
    const float* p = partials + (size_t)nh * split * KVSZ + rem;
    float s = 0.f;
    for (int c = 0; c < split; ++c) s += p[(size_t)c * KVSZ];
    kvt[idx] = s;
}

// ---------------------------------------------------------------------------
// Phase 2 (v5): register-tiled GEMM, Out[4096][65] = Qf[4096][64]*KV[64][65].
//  Per wave 64 rows x 32 cols, lane owns 8x4 tile; per k-chunk(4): 13
//  ds_read_b128 feed 160 FMAs; KV reused 8x, Q 4x in registers. Denominator
//  = KV row 64, accumulated per-lane for its own rows. Direct global stores.
//  (Round-6 measured ~20us ~= its 21us HBM floor -> unchanged.)
// ---------------------------------------------------------------------------
__global__ __launch_bounds__(256, 2)
void la_phase2(const float* __restrict__ Qin, const float* __restrict__ kvt,
               float* __restrict__ Out)
{
    __shared__ float sQ[128 * 68];   // 34.8 KB, row-major, stride 68
    __shared__ float sKV[KVSZ];      // 17.3 KB, [65][68] d-major

    const int b   = blockIdx.x;
    const int nh  = b >> 5;          // 32 l-chunks of 128 rows per (n,h)
    const int lc  = b & 31;
    const int n   = nh >> 3;
    const int h   = nh & 7;
    const int tid = threadIdx.x;
    const int w    = tid >> 6;
    const int lane = tid & 63;

    const float* Qc = Qin + (((size_t)n * L_L + (size_t)lc * 128) * H_H + h) * D_D;
    float*       Oc = Out + (((size_t)n * L_L + (size_t)lc * 128) * H_H + h) * D_D;

    // ---- stage KV_aug[65][68] into LDS (1105 float4, coalesced) ----
    {
        const float4* src = (const float4*)(kvt + (size_t)nh * KVSZ);
        float4*       dst = (float4*)sKV;
        #pragma unroll
        for (int it = 0; it < 4; ++it)
            dst[it * 256 + tid] = src[it * 256 + tid];
        if (tid < 81) dst[1024 + tid] = src[1024 + tid];
    }

    // ---- stage Q tile 128 rows x 64 cols (elu applied), stride 68 ----
    #pragma unroll
    for (int it = 0; it < 8; ++it) {
        const int slot = it * 256 + tid;   // 0..2047
        const int r    = slot >> 4;        // 0..127
        const int c4   = slot & 15;
        float4 v = *(const float4*)(Qc + (size_t)r * (H_H * D_D) + c4 * 4);
        v.x = elu1(v.x); v.y = elu1(v.y); v.z = elu1(v.z); v.w = elu1(v.w);
        *(float4*)&sQ[r * 68 + c4 * 4] = v;
    }
    __syncthreads();

    // ---- wave work assignment ----
    const int rt   = (w >> 1) * 64;        // row tile: 0 or 64
    const int wc   = w & 1;                // col half: 0 or 1
    const int rl   = lane & 7;             // row lane: rows rt + rl + 8j
    const int cg   = lane >> 3;            // col group
    const int ccol = wc * 32 + cg * 4;     // this lane's 4 output cols

    float acc[8][4];
    float den[8];
    #pragma unroll
    for (int j = 0; j < 8; ++j) {
        den[j] = 0.f;
        #pragma unroll
        for (int m = 0; m < 4; ++m) acc[j][m] = 0.f;
    }

    const int qbase = rt + rl;             // + 8j, stride-68 rows

    for (int kc = 0; kc < 16; ++kc) {
        // Q fragments: 8 rows x 4 k  (conflict-free b128: banks partition)
        float4 qv[8];
        #pragma unroll
        for (int j = 0; j < 8; ++j)
            qv[j] = *(const float4*)&sQ[(qbase + 8 * j) * 68 + kc * 4];
        // KV fragments: 4 k-rows x lane's 4 cols (conflict-free)
        const float4 kv0 = *(const float4*)&sKV[(kc * 4 + 0) * KVLD + ccol];
        const float4 kv1 = *(const float4*)&sKV[(kc * 4 + 1) * KVLD + ccol];
        const float4 kv2 = *(const float4*)&sKV[(kc * 4 + 2) * KVLD + ccol];
        const float4 kv3 = *(const float4*)&sKV[(kc * 4 + 3) * KVLD + ccol];
        // K_sum fragment: wave-uniform broadcast
        const float4 ks  = *(const float4*)&sKV[64 * KVLD + kc * 4];

        #pragma unroll
        for (int j = 0; j < 8; ++j) {
            const float q0 = qv[j].x, q1 = qv[j].y, q2 = qv[j].z, q3 = qv[j].w;
            den[j] = fmaf(q0, ks.x, den[j]);
            den[j] = fmaf(q1, ks.y, den[j]);
            den[j] = fmaf(q2, ks.z, den[j]);
            den[j] = fmaf(q3, ks.w, den[j]);
            acc[j][0] = fmaf(q0, kv0.x, acc[j][0]);
            acc[j][0] = fmaf(q1, kv1.x, acc[j][0]);
            acc[j][0] = fmaf(q2, kv2.x, acc[j][0]);
            acc[j][0] = fmaf(q3, kv3.x, acc[j][0]);
            acc[j][1] = fmaf(q0, kv0.y, acc[j][1]);
            acc[j][1] = fmaf(q1, kv1.y, acc[j][1]);
            acc[j][1] = fmaf(q2, kv2.y, acc[j][1]);
            acc[j][1] = fmaf(q3, kv3.y, acc[j][1]);
            acc[j][2] = fmaf(q0, kv0.z, acc[j][2]);
            acc[j][2] = fmaf(q1, kv1.z, acc[j][2]);
            acc[j][2] = fmaf(q2, kv2.z, acc[j][2]);
            acc[j][2] = fmaf(q3, kv3.z, acc[j][2]);
            acc[j][3] = fmaf(q0, kv0.w, acc[j][3]);
            acc[j][3] = fmaf(q1, kv1.w, acc[j][3]);
            acc[j][3] = fmaf(q2, kv2.w, acc[j][3]);
            acc[j][3] = fmaf(q3, kv3.w, acc[j][3]);
        }
    }

    // ---- epilogue: scale by 1/(den+eps), direct coalesced global stores ----
    #pragma unroll
    for (int j = 0; j < 8; ++j) {
        const float rz = 1.0f / (den[j] + 1e-6f);
        *(float4*)(Oc + (size_t)(qbase + 8 * j) * (H_H * D_D) + ccol) =
            make_float4(acc[j][0] * rz, acc[j][1] * rz,
                        acc[j][2] * rz, acc[j][3] * rz);
    }
}

// ---------------------------------------------------------------------------
extern "C" void kernel_launch(void* const* d_in, const int* in_sizes, int n_in,
                              void* d_out, int out_size, void* d_ws, size_t ws_size,
                              hipStream_t stream)
{
    const float* Q = (const float*)d_in[0];
    const float* K = (const float*)d_in[1];
    const float* V = (const float*)d_in[2];
    float* out = (float*)d_out;

    // ws layout: [ kvt: NH*KVSZ floats ][ partials: NH*split*KVSZ floats ]
    float* kvt = (float*)d_ws;
    const size_t kvt_bytes = (size_t)NH * KVSZ * sizeof(float);

    int split = 16;
    while (split > 1 &&
           kvt_bytes + (size_t)NH * split * KVSZ * sizeof(float) > ws_size)
        split >>= 1;
    float* partials = kvt + (size_t)NH * KVSZ;
    const int schunk = S_S / split;

    la_phase1<<<NH * split, 256, 0, stream>>>(K, V, partials, split, schunk);

    const int red_blocks = (NH * KVSZ + 255) / 256;   // 1105 exactly
    la_reduce<<<red_blocks, 256, 0, stream>>>(partials, kvt, split);

    la_phase2<<<NH * (L_L / 128), 256, 0, stream>>>(Q, kvt, out);
}

// Round 16
// 197.207 us; speedup vs baseline: 1.5916x; 1.5916x over previous
//
#include <hip/hip_runtime.h>
#include <hip/hip_bf16.h>
#include <cstddef>
#include <cstdint>

// Problem constants (fixed by the reference setup)
#define N_B   8
#define L_L   4096
#define S_S   4096
#define H_H   8
#define D_D   64
#define NH    64          // N_B * H_H
// KV_aug layout (d-major): rows 0..63 = KV[d][v] (stride 68, cols 64..67 pad),
// row 64 = K_sum[d] (indexed by d in cols 0..63). KVSZ floats per (n,h).
#define KVLD  68
#define KVSZ  (65 * KVLD)   // 4420
#define TSTRIDE (32 * H_H * D_D)   // floats per 32-row tile step

typedef const float __attribute__((address_space(1)))* gas_fp;
typedef float __attribute__((address_space(3)))* las_fp;

__device__ __forceinline__ float elu1(float x) {
    // elu(x)+1 : x>0 ? x+1 : exp(x)
    return x > 0.f ? x + 1.f : __expf(x);
}

// ---------------------------------------------------------------------------
// Phase 1 (v11): full K+V pipeline at the 170-reg tier, no residency tail.
//  Register-cap analysis (v8-v10): launch_bounds(256,4) = 128 unified regs;
//  acc[8][8]=64 AGPR + 64 arch VGPR = exactly full in v8 (VGPR_Count=64,
//  no spill). ANY pipelining addition overflowed -> acc spilled (v9 253MB,
//  v10 620MB writes). Pipelining K needs the (256,3)=170-reg tier; v7 proved
//  it spill-free (84 VGPRs, held-K prefetch) but lost ~33% to the
//  3-resident-of-4-blocks/CU tail.
//  v11: split=8 -> 512 blocks = 2/CU, BOTH resident at (256,3): no tail.
//  Wave-private zero-barrier loop (the only structure that never spilled):
//  wave w owns s-rows w*8..w*8+7/tile. K reg-staged ONE TILE AHEAD (8 held
//  regs, v7 pattern) into double-buffered LDS K; V double-buffered via
//  global_load_lds DMA (zero regs). vmcnt(4) = exactly one tile (2 V DMAs +
//  2 K loads) in flight across each compute phase. Tile loop unrolled x2 for
//  compile-time buffer names; pointers strength-reduced (advance by TSTRIDE).
// ---------------------------------------------------------------------------
__global__ __launch_bounds__(256, 3)
void la_phase1(const float* __restrict__ Kin, const float* __restrict__ Vin,
               float* __restrict__ partials, int split, int schunk)
{
    __shared__ union {
        struct { float K0[32 * 64]; float K1[32 * 64];
                 float V0[32 * 64]; float V1[32 * 64]; } st;   // 32 KB
        float acc[64 * 68];                                    // 17.3 KB
    } sm;
    __shared__ float sKsumP[4 * 64];     // per-wave ksum partials

    const int b     = blockIdx.x;
    const int nh    = b / split;
    const int chunk = b - nh * split;
    const int n     = nh >> 3;
    const int h     = nh & 7;
    const int s0    = chunk * schunk;

    const int tid  = threadIdx.x;
    const int w    = tid >> 6;
    const int lane = tid & 63;
    const int dg   = lane >> 3;   // d-group: d = dg*8 + i
    const int vg   = lane & 7;    // v-group: v = vg*8 + j

    float acc[8][8];
    #pragma unroll
    for (int i = 0; i < 8; ++i)
        #pragma unroll
        for (int j = 0; j < 8; ++j) acc[i][j] = 0.f;
    float ksum = 0.f;

    const int kd = lane;               // ksum d index (per-wave full coverage)

    // staging map (wave-private, lane-linear within each 1024B chunk):
    // chunk c covers rows w*8+c*4..+3; lane l -> row +(l>>4), col (l&15)*4
    const int lrow = lane >> 4;        // 0..3
    const int lcol = (lane & 15) * 4;  // float col

    // per-lane source pointers, advanced by TSTRIDE per tile (no per-tile
    // address math -> no register-pressure leak)
    const size_t base = (size_t)n * S_S * (H_H * D_D) + h * D_D;
    const float* kp0 = Kin + base + (size_t)(s0 + w * 8 + 0 + lrow) * (H_H * D_D) + lcol;
    const float* kp1 = Kin + base + (size_t)(s0 + w * 8 + 4 + lrow) * (H_H * D_D) + lcol;
    const float* vp0 = Vin + base + (size_t)(s0 + w * 8 + 0 + lrow) * (H_H * D_D) + lcol;
    const float* vp1 = Vin + base + (size_t)(s0 + w * 8 + 4 + lrow) * (H_H * D_D) + lcol;

    const int ntiles = schunk >> 5;    // 16 at split=8 (always even)
    const int nt2    = ntiles >> 1;

    const int kb0 = (w * 8 + 0) * 64;  // LDS chunk bases
    const int kb1 = (w * 8 + 4) * 64;

#define ISSUE_V(VB)                                                              \
    do {                                                                         \
        __builtin_amdgcn_global_load_lds((gas_fp)vp0, (las_fp)&VB[kb0], 16, 0, 0); \
        __builtin_amdgcn_global_load_lds((gas_fp)vp1, (las_fp)&VB[kb1], 16, 0, 0); \
        vp0 += TSTRIDE; vp1 += TSTRIDE;                                          \
    } while (0)

#define LOAD_K(RA, RB)                                                           \
    do {                                                                         \
        RA = *(const float4*)kp0;  RB = *(const float4*)kp1;                     \
        kp0 += TSTRIDE; kp1 += TSTRIDE;                                          \
    } while (0)

#define STORE_K(KB, RA, RB)                                                      \
    do {                                                                         \
        RA.x = elu1(RA.x); RA.y = elu1(RA.y); RA.z = elu1(RA.z); RA.w = elu1(RA.w); \
        RB.x = elu1(RB.x); RB.y = elu1(RB.y); RB.z = elu1(RB.z); RB.w = elu1(RB.w); \
        *(float4*)&KB[kb0 + lane * 4] = RA;                                      \
        *(float4*)&KB[kb1 + lane * 4] = RB;                                      \
    } while (0)

#define COMPUTE_TILE(KB, VB)                                                     \
    do {                                                                         \
        _Pragma("unroll")                                                        \
        for (int sl = 0; sl < 8; ++sl) {                                         \
            const int s_ = w * 8 + sl;                                           \
            const float4 k0_ = *(const float4*)&KB[s_ * 64 + dg * 8];            \
            const float4 k1_ = *(const float4*)&KB[s_ * 64 + dg * 8 + 4];        \
            const float4 v0_ = *(const float4*)&VB[s_ * 64 + vg * 8];            \
            const float4 v1_ = *(const float4*)&VB[s_ * 64 + vg * 8 + 4];        \
            const float kf_[8] = {k0_.x, k0_.y, k0_.z, k0_.w,                    \
                                  k1_.x, k1_.y, k1_.z, k1_.w};                   \
            const float vf_[8] = {v0_.x, v0_.y, v0_.z, v0_.w,                    \
                                  v1_.x, v1_.y, v1_.z, v1_.w};                   \
            _Pragma("unroll")                                                    \
            for (int i = 0; i < 8; ++i)                                          \
                _Pragma("unroll")                                                \
                for (int j = 0; j < 8; ++j)                                      \
                    acc[i][j] = fmaf(kf_[i], vf_[j], acc[i][j]);                 \
        }                                                                        \
        _Pragma("unroll")                                                        \
        for (int sl = 0; sl < 8; ++sl)                                           \
            ksum += KB[(w * 8 + sl) * 64 + kd];                                  \
    } while (0)

    float4 ka, kb;

    // ---- prologue: V(0) DMA -> V0; K(0) -> regs -> elu -> K0 ----
    ISSUE_V(sm.st.V0);
    LOAD_K(ka, kb);
    STORE_K(sm.st.K0, ka, kb);

    for (int tt = 0; tt < nt2; ++tt) {
        // half A: consume buffers 0 (tile 2tt); prefetch tile 2tt+1 -> buffers 1
        ISSUE_V(sm.st.V1);
        LOAD_K(ka, kb);                       // held across compute (8 regs)
        // 4 newest outstanding (V1 DMAs + K loads); older V0 DMAs drained:
        asm volatile("s_waitcnt vmcnt(4)" ::: "memory");
        COMPUTE_TILE(sm.st.K0, sm.st.V0);
        STORE_K(sm.st.K1, ka, kb);            // K(2tt+1) ready

        // half B: consume buffers 1 (tile 2tt+1); prefetch 2tt+2 -> buffers 0
        if (tt + 1 < nt2) {
            ISSUE_V(sm.st.V0);
            LOAD_K(ka, kb);
            asm volatile("s_waitcnt vmcnt(4)" ::: "memory");
            COMPUTE_TILE(sm.st.K1, sm.st.V1);
            STORE_K(sm.st.K0, ka, kb);
        } else {
            asm volatile("s_waitcnt vmcnt(0)" ::: "memory");
            COMPUTE_TILE(sm.st.K1, sm.st.V1);
        }
    }
#undef ISSUE_V
#undef LOAD_K
#undef STORE_K
#undef COMPUTE_TILE

    __syncthreads();   // loop done (implicit full drain); sm.acc (union) safe

    // cross-wave reduce of acc into sm.acc[d][v] (stride 68), sequential & exact
    for (int ww = 0; ww < 4; ++ww) {
        if (w == ww) {
            #pragma unroll
            for (int i = 0; i < 8; ++i) {
                float* p = &sm.acc[(dg * 8 + i) * 68 + vg * 8];
                if (ww == 0) {
                    *(float4*)p       = make_float4(acc[i][0], acc[i][1], acc[i][2], acc[i][3]);
                    *(float4*)(p + 4) = make_float4(acc[i][4], acc[i][5], acc[i][6], acc[i][7]);
                } else {
                    float4 a0 = *(const float4*)p;
                    float4 a1 = *(const float4*)(p + 4);
                    a0.x += acc[i][0]; a0.y += acc[i][1]; a0.z += acc[i][2]; a0.w += acc[i][3];
                    a1.x += acc[i][4]; a1.y += acc[i][5]; a1.z += acc[i][6]; a1.w += acc[i][7];
                    *(float4*)p       = a0;
                    *(float4*)(p + 4) = a1;
                }
            }
        }
        __syncthreads();
    }

    // ksum: deterministic 4-way reduce (one slot per (wave, d))
    sKsumP[w * 64 + kd] = ksum;
    __syncthreads();

    // write this block's partial KV_aug[65][68] d-major (row 64 = K_sum, pads 0)
    float* outp = partials + (size_t)b * KVSZ;
    for (int idx = tid; idx < KVSZ; idx += 256) {
        const int r = idx / KVLD;
        const int c = idx - r * KVLD;
        float val = 0.f;
        if (c < 64) {
            if (r < 64)
                val = sm.acc[idx];   // sm.acc is [d][v] stride 68 == same layout
            else
                val = sKsumP[c] + sKsumP[64 + c] + sKsumP[128 + c] + sKsumP[192 + c];
        }
        outp[idx] = val;
    }
}

// ---------------------------------------------------------------------------
// Reduce: sum the `split` partials per (n,h) -> kvt[nh][65][68]
// ---------------------------------------------------------------------------
__global__ __launch_bounds__(256)
void la_reduce(const float* __restrict__ partials, float* __restrict__ kvt, int split)
{
    const int idx = blockIdx.x * 256 + threadIdx.x;
    if (idx >= NH * KVSZ) return;
    const int nh  = idx / KVSZ;
    const int rem = idx - nh * KVSZ;
    const float* p = partials + (size_t)nh * split * KVSZ + rem;
    float s = 0.f;
    for (int c = 0; c < split; ++c) s += p[(size_t)c * KVSZ];
    kvt[idx] = s;
}

// ---------------------------------------------------------------------------
// Phase 2 (v5): register-tiled GEMM, Out[4096][65] = Qf[4096][64]*KV[64][65].
//  Per wave 64 rows x 32 cols, lane owns 8x4 tile; per k-chunk(4): 13
//  ds_read_b128 feed 160 FMAs; KV reused 8x, Q 4x in registers. Denominator
//  = KV row 64, accumulated per-lane for its own rows. Direct global stores.
//  (Round-6 measured ~20us ~= its 21us HBM floor -> unchanged.)
// ---------------------------------------------------------------------------
__global__ __launch_bounds__(256, 2)
void la_phase2(const float* __restrict__ Qin, const float* __restrict__ kvt,
               float* __restrict__ Out)
{
    __shared__ float sQ[128 * 68];   // 34.8 KB, row-major, stride 68
    __shared__ float sKV[KVSZ];      // 17.3 KB, [65][68] d-major

    const int b   = blockIdx.x;
    const int nh  = b >> 5;          // 32 l-chunks of 128 rows per (n,h)
    const int lc  = b & 31;
    const int n   = nh >> 3;
    const int h   = nh & 7;
    const int tid = threadIdx.x;
    const int w    = tid >> 6;
    const int lane = tid & 63;

    const float* Qc = Qin + (((size_t)n * L_L + (size_t)lc * 128) * H_H + h) * D_D;
    float*       Oc = Out + (((size_t)n * L_L + (size_t)lc * 128) * H_H + h) * D_D;

    // ---- stage KV_aug[65][68] into LDS (1105 float4, coalesced) ----
    {
        const float4* src = (const float4*)(kvt + (size_t)nh * KVSZ);
        float4*       dst = (float4*)sKV;
        #pragma unroll
        for (int it = 0; it < 4; ++it)
            dst[it * 256 + tid] = src[it * 256 + tid];
        if (tid < 81) dst[1024 + tid] = src[1024 + tid];
    }

    // ---- stage Q tile 128 rows x 64 cols (elu applied), stride 68 ----
    #pragma unroll
    for (int it = 0; it < 8; ++it) {
        const int slot = it * 256 + tid;   // 0..2047
        const int r    = slot >> 4;        // 0..127
        const int c4   = slot & 15;
        float4 v = *(const float4*)(Qc + (size_t)r * (H_H * D_D) + c4 * 4);
        v.x = elu1(v.x); v.y = elu1(v.y); v.z = elu1(v.z); v.w = elu1(v.w);
        *(float4*)&sQ[r * 68 + c4 * 4] = v;
    }
    __syncthreads();

    // ---- wave work assignment ----
    const int rt   = (w >> 1) * 64;        // row tile: 0 or 64
    const int wc   = w & 1;                // col half: 0 or 1
    const int rl   = lane & 7;             // row lane: rows rt + rl + 8j
    const int cg   = lane >> 3;            // col group
    const int ccol = wc * 32 + cg * 4;     // this lane's 4 output cols

    float acc[8][4];
    float den[8];
    #pragma unroll
    for (int j = 0; j < 8; ++j) {
        den[j] = 0.f;
        #pragma unroll
        for (int m = 0; m < 4; ++m) acc[j][m] = 0.f;
    }

    const int qbase = rt + rl;             // + 8j, stride-68 rows

    for (int kc = 0; kc < 16; ++kc) {
        // Q fragments: 8 rows x 4 k  (conflict-free b128: banks partition)
        float4 qv[8];
        #pragma unroll
        for (int j = 0; j < 8; ++j)
            qv[j] = *(const float4*)&sQ[(qbase + 8 * j) * 68 + kc * 4];
        // KV fragments: 4 k-rows x lane's 4 cols (conflict-free)
        const float4 kv0 = *(const float4*)&sKV[(kc * 4 + 0) * KVLD + ccol];
        const float4 kv1 = *(const float4*)&sKV[(kc * 4 + 1) * KVLD + ccol];
        const float4 kv2 = *(const float4*)&sKV[(kc * 4 + 2) * KVLD + ccol];
        const float4 kv3 = *(const float4*)&sKV[(kc * 4 + 3) * KVLD + ccol];
        // K_sum fragment: wave-uniform broadcast
        const float4 ks  = *(const float4*)&sKV[64 * KVLD + kc * 4];

        #pragma unroll
        for (int j = 0; j < 8; ++j) {
            const float q0 = qv[j].x, q1 = qv[j].y, q2 = qv[j].z, q3 = qv[j].w;
            den[j] = fmaf(q0, ks.x, den[j]);
            den[j] = fmaf(q1, ks.y, den[j]);
            den[j] = fmaf(q2, ks.z, den[j]);
            den[j] = fmaf(q3, ks.w, den[j]);
            acc[j][0] = fmaf(q0, kv0.x, acc[j][0]);
            acc[j][0] = fmaf(q1, kv1.x, acc[j][0]);
            acc[j][0] = fmaf(q2, kv2.x, acc[j][0]);
            acc[j][0] = fmaf(q3, kv3.x, acc[j][0]);
            acc[j][1] = fmaf(q0, kv0.y, acc[j][1]);
            acc[j][1] = fmaf(q1, kv1.y, acc[j][1]);
            acc[j][1] = fmaf(q2, kv2.y, acc[j][1]);
            acc[j][1] = fmaf(q3, kv3.y, acc[j][1]);
            acc[j][2] = fmaf(q0, kv0.z, acc[j][2]);
            acc[j][2] = fmaf(q1, kv1.z, acc[j][2]);
            acc[j][2] = fmaf(q2, kv2.z, acc[j][2]);
            acc[j][2] = fmaf(q3, kv3.z, acc[j][2]);
            acc[j][3] = fmaf(q0, kv0.w, acc[j][3]);
            acc[j][3] = fmaf(q1, kv1.w, acc[j][3]);
            acc[j][3] = fmaf(q2, kv2.w, acc[j][3]);
            acc[j][3] = fmaf(q3, kv3.w, acc[j][3]);
        }
    }

    // ---- epilogue: scale by 1/(den+eps), direct coalesced global stores ----
    #pragma unroll
    for (int j = 0; j < 8; ++j) {
        const float rz = 1.0f / (den[j] + 1e-6f);
        *(float4*)(Oc + (size_t)(qbase + 8 * j) * (H_H * D_D) + ccol) =
            make_float4(acc[j][0] * rz, acc[j][1] * rz,
                        acc[j][2] * rz, acc[j][3] * rz);
    }
}

// ---------------------------------------------------------------------------
extern "C" void kernel_launch(void* const* d_in, const int* in_sizes, int n_in,
                              void* d_out, int out_size, void* d_ws, size_t ws_size,
                              hipStream_t stream)
{
    const float* Q = (const float*)d_in[0];
    const float* K = (const float*)d_in[1];
    const float* V = (const float*)d_in[2];
    float* out = (float*)d_out;

    // ws layout: [ kvt: NH*KVSZ floats ][ partials: NH*split*KVSZ floats ]
    float* kvt = (float*)d_ws;
    const size_t kvt_bytes = (size_t)NH * KVSZ * sizeof(float);

    int split = 8;    // 512 blocks = 2/CU, both resident at (256,3): no tail
    while (split > 1 &&
           kvt_bytes + (size_t)NH * split * KVSZ * sizeof(float) > ws_size)
        split >>= 1;
    float* partials = kvt + (size_t)NH * KVSZ;
    const int schunk = S_S / split;

    la_phase1<<<NH * split, 256, 0, stream>>>(K, V, partials, split, schunk);

    const int red_blocks = (NH * KVSZ + 255) / 256;   // 1105 exactly
    la_reduce<<<red_blocks, 256, 0, stream>>>(partials, kvt, split);

    la_phase2<<<NH * (L_L / 128), 256, 0, stream>>>(Q, kvt, out);
}

// Round 17
// 90.617 us; speedup vs baseline: 3.4638x; 2.1763x over previous
//
#include <hip/hip_runtime.h>
#include <hip/hip_bf16.h>
#include <cstddef>
#include <cstdint>

// Problem constants (fixed by the reference setup)
#define N_B   8
#define L_L   4096
#define S_S   4096
#define H_H   8
#define D_D   64
#define NH    64          // N_B * H_H
// KV_aug layout (d-major): rows 0..63 = KV[d][v] (stride 68, cols 64..67 pad),
// row 64 = K_sum[d] (indexed by d in cols 0..63). KVSZ floats per (n,h).
#define KVLD  68
#define KVSZ  (65 * KVLD)   // 4420

typedef const float __attribute__((address_space(1)))* gas_fp;
typedef float __attribute__((address_space(3)))* las_fp;

__device__ __forceinline__ float elu1(float x) {
    // elu(x)+1 : x>0 ? x+1 : exp(x)
    return x > 0.f ? x + 1.f : __expf(x);
}

// ---------------------------------------------------------------------------
// Phase 1 (v12): held-K prefetch at the 256-reg tier with pinned schedule.
//  Ledger v7-v11: (256,4)=128 regs is exactly full (acc 64 AGPR + 64 arch) —
//  any pipelining spills (v9 253MB, v10 620MB writes). v7's K was consumed
//  immediately -> compiler vmcnt drain every tile (VALU 30%). v11 deferred
//  the store but (a) compiler hoisted it (no alias info) and (b) 2 blocks/CU
//  at a 3-block cap -> Occ 21%.
//  v12: __launch_bounds__(256,2) -> 256-reg cap: acc 64 + ~120 arch fits
//  with slack (spill impossible). split=8 -> 512 blocks = exactly 2
//  resident/CU (LDS 49KB x2), 8 waves/CU on all 4 SIMDs. Per 64-row tile:
//  issue V(t+1) DMA (4 chunks, no regs) + load K(t+1) into 16 HELD regs |
//  sched_barrier | compute(t) (2048cy, covers the loads) | sched_barrier |
//  vmcnt(0) + elu + lane-linear store K(t+1). The only memory wait sits
//  AFTER the compute -> zero exposed latency. Zero block barriers in loop
//  (all staging wave-private: wave w owns s-rows w*16..w*16+15).
// ---------------------------------------------------------------------------
__global__ __launch_bounds__(256, 2)
void la_phase1(const float* __restrict__ Kin, const float* __restrict__ Vin,
               float* __restrict__ partials, int split, int schunk)
{
    __shared__ union {
        struct { float K[64 * 64]; float V[2][64 * 64]; } st;  // 48 KB
        float acc[64 * 68];                                    // 17.3 KB
    } sm;
    __shared__ float sKsumP[4 * 64];     // per-wave ksum partials

    const int b     = blockIdx.x;
    const int nh    = b / split;
    const int chunk = b - nh * split;
    const int n     = nh >> 3;
    const int h     = nh & 7;
    const int s0    = chunk * schunk;

    const int tid  = threadIdx.x;
    const int w    = tid >> 6;
    const int lane = tid & 63;
    const int dg   = lane >> 3;   // d-group: d = dg*8 + i
    const int vg   = lane & 7;    // v-group: v = vg*8 + j

    float acc[8][8];
    #pragma unroll
    for (int i = 0; i < 8; ++i)
        #pragma unroll
        for (int j = 0; j < 8; ++j) acc[i][j] = 0.f;
    float ksum = 0.f;

    const int kd = lane;               // ksum d index (per-wave full coverage)

    // staging map: chunk c covers rows w*16+c*4..+3; lane l -> row +(l>>4),
    // col (l&15)*4 (16B); LDS dest lane-linear (conflict-free b128 writes).
    const int lrow = lane >> 4;        // 0..3
    const int lcol = (lane & 15) * 4;  // float col

    const float* Kb = Kin + (size_t)n * S_S * (H_H * D_D) + h * D_D;
    const float* Vb = Vin + (size_t)n * S_S * (H_H * D_D) + h * D_D;

    const int ntiles = schunk >> 6;    // tiles of 64 s-rows (8 at split=8)

    float4 ka0, ka1, ka2, ka3;         // held K prefetch (16 regs)

#define ELU4(X) do { X.x = elu1(X.x); X.y = elu1(X.y); \
                     X.z = elu1(X.z); X.w = elu1(X.w); } while (0)

    // ---- prologue: tile 0 ----
    {
        #pragma unroll
        for (int c = 0; c < 4; ++c) {
            __builtin_amdgcn_global_load_lds(
                (gas_fp)(Vb + (size_t)(s0 + w * 16 + c * 4 + lrow) * (H_H * D_D) + lcol),
                (las_fp)&sm.st.V[0][(w * 16 + c * 4) * 64], 16, 0, 0);
        }
        ka0 = *(const float4*)(Kb + (size_t)(s0 + w * 16 +  0 + lrow) * (H_H * D_D) + lcol);
        ka1 = *(const float4*)(Kb + (size_t)(s0 + w * 16 +  4 + lrow) * (H_H * D_D) + lcol);
        ka2 = *(const float4*)(Kb + (size_t)(s0 + w * 16 +  8 + lrow) * (H_H * D_D) + lcol);
        ka3 = *(const float4*)(Kb + (size_t)(s0 + w * 16 + 12 + lrow) * (H_H * D_D) + lcol);
        asm volatile("s_waitcnt vmcnt(0)" ::: "memory");
        ELU4(ka0); ELU4(ka1); ELU4(ka2); ELU4(ka3);
        *(float4*)&sm.st.K[(w * 16 +  0) * 64 + lane * 4] = ka0;
        *(float4*)&sm.st.K[(w * 16 +  4) * 64 + lane * 4] = ka1;
        *(float4*)&sm.st.K[(w * 16 +  8) * 64 + lane * 4] = ka2;
        *(float4*)&sm.st.K[(w * 16 + 12) * 64 + lane * 4] = ka3;
    }

    for (int t = 0; t < ntiles; ++t) {
        const bool more = (t + 1 < ntiles);

        // ---- region 1: issue tile t+1 (V DMA, no regs; K into held regs) ----
        if (more) {
            const int srn = s0 + (t + 1) * 64;
            float* vdst = sm.st.V[(t + 1) & 1];
            #pragma unroll
            for (int c = 0; c < 4; ++c) {
                __builtin_amdgcn_global_load_lds(
                    (gas_fp)(Vb + (size_t)(srn + w * 16 + c * 4 + lrow) * (H_H * D_D) + lcol),
                    (las_fp)&vdst[(w * 16 + c * 4) * 64], 16, 0, 0);
            }
            ka0 = *(const float4*)(Kb + (size_t)(srn + w * 16 +  0 + lrow) * (H_H * D_D) + lcol);
            ka1 = *(const float4*)(Kb + (size_t)(srn + w * 16 +  4 + lrow) * (H_H * D_D) + lcol);
            ka2 = *(const float4*)(Kb + (size_t)(srn + w * 16 +  8 + lrow) * (H_H * D_D) + lcol);
            ka3 = *(const float4*)(Kb + (size_t)(srn + w * 16 + 12 + lrow) * (H_H * D_D) + lcol);
        }
        __builtin_amdgcn_sched_barrier(0);   // pin: issue | compute

        // ---- region 2: compute tile t (covers the in-flight loads) ----
        {
            const float* Kbuf = sm.st.K;
            const float* Vbuf = sm.st.V[t & 1];
            #pragma unroll 4
            for (int sl = 0; sl < 16; ++sl) {
                const int s = w * 16 + sl;
                const float4 k0 = *(const float4*)&Kbuf[s * 64 + dg * 8];
                const float4 k1 = *(const float4*)&Kbuf[s * 64 + dg * 8 + 4];
                const float4 v0 = *(const float4*)&Vbuf[s * 64 + vg * 8];
                const float4 v1 = *(const float4*)&Vbuf[s * 64 + vg * 8 + 4];
                const float kf[8] = {k0.x, k0.y, k0.z, k0.w, k1.x, k1.y, k1.z, k1.w};
                const float vf[8] = {v0.x, v0.y, v0.z, v0.w, v1.x, v1.y, v1.z, v1.w};
                #pragma unroll
                for (int i = 0; i < 8; ++i)
                    #pragma unroll
                    for (int j = 0; j < 8; ++j)
                        acc[i][j] = fmaf(kf[i], vf[j], acc[i][j]);
            }
            #pragma unroll
            for (int sl = 0; sl < 16; ++sl)
                ksum += Kbuf[(w * 16 + sl) * 64 + kd];
        }
        __builtin_amdgcn_sched_barrier(0);   // pin: compute | drain+store

        // ---- region 3: drain (loads have had ~2048cy), elu, store K(t+1) ----
        if (more) {
            asm volatile("s_waitcnt vmcnt(0)" ::: "memory");
            ELU4(ka0); ELU4(ka1); ELU4(ka2); ELU4(ka3);
            *(float4*)&sm.st.K[(w * 16 +  0) * 64 + lane * 4] = ka0;
            *(float4*)&sm.st.K[(w * 16 +  4) * 64 + lane * 4] = ka1;
            *(float4*)&sm.st.K[(w * 16 +  8) * 64 + lane * 4] = ka2;
            *(float4*)&sm.st.K[(w * 16 + 12) * 64 + lane * 4] = ka3;
        }
    }
#undef ELU4

    __syncthreads();   // loop done (implicit full drain); sm.acc (union) safe

    // cross-wave reduce of acc into sm.acc[d][v] (stride 68), sequential & exact
    for (int ww = 0; ww < 4; ++ww) {
        if (w == ww) {
            #pragma unroll
            for (int i = 0; i < 8; ++i) {
                float* p = &sm.acc[(dg * 8 + i) * 68 + vg * 8];
                if (ww == 0) {
                    *(float4*)p       = make_float4(acc[i][0], acc[i][1], acc[i][2], acc[i][3]);
                    *(float4*)(p + 4) = make_float4(acc[i][4], acc[i][5], acc[i][6], acc[i][7]);
                } else {
                    float4 a0 = *(const float4*)p;
                    float4 a1 = *(const float4*)(p + 4);
                    a0.x += acc[i][0]; a0.y += acc[i][1]; a0.z += acc[i][2]; a0.w += acc[i][3];
                    a1.x += acc[i][4]; a1.y += acc[i][5]; a1.z += acc[i][6]; a1.w += acc[i][7];
                    *(float4*)p       = a0;
                    *(float4*)(p + 4) = a1;
                }
            }
        }
        __syncthreads();
    }

    // ksum: deterministic 4-way reduce (one slot per (wave, d))
    sKsumP[w * 64 + kd] = ksum;
    __syncthreads();

    // write this block's partial KV_aug[65][68] d-major (row 64 = K_sum, pads 0)
    float* outp = partials + (size_t)b * KVSZ;
    for (int idx = tid; idx < KVSZ; idx += 256) {
        const int r = idx / KVLD;
        const int c = idx - r * KVLD;
        float val = 0.f;
        if (c < 64) {
            if (r < 64)
                val = sm.acc[idx];   // sm.acc is [d][v] stride 68 == same layout
            else
                val = sKsumP[c] + sKsumP[64 + c] + sKsumP[128 + c] + sKsumP[192 + c];
        }
        outp[idx] = val;
    }
}

// ---------------------------------------------------------------------------
// Reduce: sum the `split` partials per (n,h) -> kvt[nh][65][68]
// ---------------------------------------------------------------------------
__global__ __launch_bounds__(256)
void la_reduce(const float* __restrict__ partials, float* __restrict__ kvt, int split)
{
    const int idx = blockIdx.x * 256 + threadIdx.x;
    if (idx >= NH * KVSZ) return;
    const int nh  = idx / KVSZ;
    const int rem = idx - nh * KVSZ;
    const float* p = partials + (size_t)nh * split * KVSZ + rem;
    float s = 0.f;
    for (int c = 0; c < split; ++c) s += p[(size_t)c * KVSZ];
    kvt[idx] = s;
}

// ---------------------------------------------------------------------------
// Phase 2 (v5): register-tiled GEMM, Out[4096][65] = Qf[4096][64]*KV[64][65].
//  Per wave 64 rows x 32 cols, lane owns 8x4 tile; per k-chunk(4): 13
//  ds_read_b128 feed 160 FMAs; KV reused 8x, Q 4x in registers. Denominator
//  = KV row 64, accumulated per-lane for its own rows. Direct global stores.
//  (Round-6 measured ~20us ~= its 21us HBM floor -> unchanged.)
// ---------------------------------------------------------------------------
__global__ __launch_bounds__(256, 2)
void la_phase2(const float* __restrict__ Qin, const float* __restrict__ kvt,
               float* __restrict__ Out)
{
    __shared__ float sQ[128 * 68];   // 34.8 KB, row-major, stride 68
    __shared__ float sKV[KVSZ];      // 17.3 KB, [65][68] d-major

    const int b   = blockIdx.x;
    const int nh  = b >> 5;          // 32 l-chunks of 128 rows per (n,h)
    const int lc  = b & 31;
    const int n   = nh >> 3;
    const int h   = nh & 7;
    const int tid = threadIdx.x;
    const int w    = tid >> 6;
    const int lane = tid & 63;

    const float* Qc = Qin + (((size_t)n * L_L + (size_t)lc * 128) * H_H + h) * D_D;
    float*       Oc = Out + (((size_t)n * L_L + (size_t)lc * 128) * H_H + h) * D_D;

    // ---- stage KV_aug[65][68] into LDS (1105 float4, coalesced) ----
    {
        const float4* src = (const float4*)(kvt + (size_t)nh * KVSZ);
        float4*       dst = (float4*)sKV;
        #pragma unroll
        for (int it = 0; it < 4; ++it)
            dst[it * 256 + tid] = src[it * 256 + tid];
        if (tid < 81) dst[1024 + tid] = src[1024 + tid];
    }

    // ---- stage Q tile 128 rows x 64 cols (elu applied), stride 68 ----
    #pragma unroll
    for (int it = 0; it < 8; ++it) {
        const int slot = it * 256 + tid;   // 0..2047
        const int r    = slot >> 4;        // 0..127
        const int c4   = slot & 15;
        float4 v = *(const float4*)(Qc + (size_t)r * (H_H * D_D) + c4 * 4);
        v.x = elu1(v.x); v.y = elu1(v.y); v.z = elu1(v.z); v.w = elu1(v.w);
        *(float4*)&sQ[r * 68 + c4 * 4] = v;
    }
    __syncthreads();

    // ---- wave work assignment ----
    const int rt   = (w >> 1) * 64;        // row tile: 0 or 64
    const int wc   = w & 1;                // col half: 0 or 1
    const int rl   = lane & 7;             // row lane: rows rt + rl + 8j
    const int cg   = lane >> 3;            // col group
    const int ccol = wc * 32 + cg * 4;     // this lane's 4 output cols

    float acc[8][4];
    float den[8];
    #pragma unroll
    for (int j = 0; j < 8; ++j) {
        den[j] = 0.f;
        #pragma unroll
        for (int m = 0; m < 4; ++m) acc[j][m] = 0.f;
    }

    const int qbase = rt + rl;             // + 8j, stride-68 rows

    for (int kc = 0; kc < 16; ++kc) {
        // Q fragments: 8 rows x 4 k  (conflict-free b128: banks partition)
        float4 qv[8];
        #pragma unroll
        for (int j = 0; j < 8; ++j)
            qv[j] = *(const float4*)&sQ[(qbase + 8 * j) * 68 + kc * 4];
        // KV fragments: 4 k-rows x lane's 4 cols (conflict-free)
        const float4 kv0 = *(const float4*)&sKV[(kc * 4 + 0) * KVLD + ccol];
        const float4 kv1 = *(const float4*)&sKV[(kc * 4 + 1) * KVLD + ccol];
        const float4 kv2 = *(const float4*)&sKV[(kc * 4 + 2) * KVLD + ccol];
        const float4 kv3 = *(const float4*)&sKV[(kc * 4 + 3) * KVLD + ccol];
        // K_sum fragment: wave-uniform broadcast
        const float4 ks  = *(const float4*)&sKV[64 * KVLD + kc * 4];

        #pragma unroll
        for (int j = 0; j < 8; ++j) {
            const float q0 = qv[j].x, q1 = qv[j].y, q2 = qv[j].z, q3 = qv[j].w;
            den[j] = fmaf(q0, ks.x, den[j]);
            den[j] = fmaf(q1, ks.y, den[j]);
            den[j] = fmaf(q2, ks.z, den[j]);
            den[j] = fmaf(q3, ks.w, den[j]);
            acc[j][0] = fmaf(q0, kv0.x, acc[j][0]);
            acc[j][0] = fmaf(q1, kv1.x, acc[j][0]);
            acc[j][0] = fmaf(q2, kv2.x, acc[j][0]);
            acc[j][0] = fmaf(q3, kv3.x, acc[j][0]);
            acc[j][1] = fmaf(q0, kv0.y, acc[j][1]);
            acc[j][1] = fmaf(q1, kv1.y, acc[j][1]);
            acc[j][1] = fmaf(q2, kv2.y, acc[j][1]);
            acc[j][1] = fmaf(q3, kv3.y, acc[j][1]);
            acc[j][2] = fmaf(q0, kv0.z, acc[j][2]);
            acc[j][2] = fmaf(q1, kv1.z, acc[j][2]);
            acc[j][2] = fmaf(q2, kv2.z, acc[j][2]);
            acc[j][2] = fmaf(q3, kv3.z, acc[j][2]);
            acc[j][3] = fmaf(q0, kv0.w, acc[j][3]);
            acc[j][3] = fmaf(q1, kv1.w, acc[j][3]);
            acc[j][3] = fmaf(q2, kv2.w, acc[j][3]);
            acc[j][3] = fmaf(q3, kv3.w, acc[j][3]);
        }
    }

    // ---- epilogue: scale by 1/(den+eps), direct coalesced global stores ----
    #pragma unroll
    for (int j = 0; j < 8; ++j) {
        const float rz = 1.0f / (den[j] + 1e-6f);
        *(float4*)(Oc + (size_t)(qbase + 8 * j) * (H_H * D_D) + ccol) =
            make_float4(acc[j][0] * rz, acc[j][1] * rz,
                        acc[j][2] * rz, acc[j][3] * rz);
    }
}

// ---------------------------------------------------------------------------
extern "C" void kernel_launch(void* const* d_in, const int* in_sizes, int n_in,
                              void* d_out, int out_size, void* d_ws, size_t ws_size,
                              hipStream_t stream)
{
    const float* Q = (const float*)d_in[0];
    const float* K = (const float*)d_in[1];
    const float* V = (const float*)d_in[2];
    float* out = (float*)d_out;

    // ws layout: [ kvt: NH*KVSZ floats ][ partials: NH*split*KVSZ floats ]
    float* kvt = (float*)d_ws;
    const size_t kvt_bytes = (size_t)NH * KVSZ * sizeof(float);

    int split = 8;    // 512 blocks = exactly 2 resident blocks/CU at (256,2)
    while (split > 1 &&
           kvt_bytes + (size_t)NH * split * KVSZ * sizeof(float) > ws_size)
        split >>= 1;
    float* partials = kvt + (size_t)NH * KVSZ;
    const int schunk = S_S / split;

    la_phase1<<<NH * split, 256, 0, stream>>>(K, V, partials, split, schunk);

    const int red_blocks = (NH * KVSZ + 255) / 256;   // 1105 exactly
    la_reduce<<<red_blocks, 256, 0, stream>>>(partials, kvt, split);

    la_phase2<<<NH * (L_L / 128), 256, 0, stream>>>(Q, kvt, out);
}